// Round 7
// baseline (2341.830 us; speedup 1.0000x reference)
//
#include <hip/hip_runtime.h>
#include <hip/hip_bf16.h>

#define T_DIM 512
#define H_DIM 4096
#define F_DIM 14336
#define KSEG  4   // split-K segments for down GEMM (14336/4 = 3584 = 56 x 64)

typedef __fp16 f16x8 __attribute__((ext_vector_type(8)));
typedef __fp16 f16x2 __attribute__((ext_vector_type(2)));
typedef float f32x4 __attribute__((ext_vector_type(4)));

// Zero d_out (harness poisons with 0xAA; down_kernel accumulates via atomics).
__global__ __launch_bounds__(256) void zero_out(float4* __restrict__ out) {
    out[blockIdx.x * 256 + threadIdx.x] = make_float4(0.f, 0.f, 0.f, 0.f);
}

// X fp32 -> f16 once (f16: 10-bit mantissa beats bf16; values ~N(0,1) safe).
__global__ __launch_bounds__(256) void cvt_x(const float* __restrict__ X,
                                             _Float16* __restrict__ Xh) {
    int i = (blockIdx.x * 256 + threadIdx.x) * 4;
    float4 v = *(const float4*)&X[i];
    union { struct { f16x2 a, b; } p; uint2 u; } u;
    u.p.a = __builtin_amdgcn_cvt_pkrtz(v.x, v.y);
    u.p.b = __builtin_amdgcn_cvt_pkrtz(v.z, v.w);
    *(uint2*)&Xh[i] = u.u;
}

// Dequant 8 int32 HQQ values -> f16x8 fragment: q*s + (-z*s), pack via pkrtz.
__device__ __forceinline__ f16x8 dq8(int4 a, int4 b, float s, float nzs) {
    float f0 = fmaf((float)a.x, s, nzs), f1 = fmaf((float)a.y, s, nzs);
    float f2 = fmaf((float)a.z, s, nzs), f3 = fmaf((float)a.w, s, nzs);
    float f4 = fmaf((float)b.x, s, nzs), f5 = fmaf((float)b.y, s, nzs);
    float f6 = fmaf((float)b.z, s, nzs), f7 = fmaf((float)b.w, s, nzs);
    union { f16x8 v; f16x2 p[4]; } u;
    u.p[0] = __builtin_amdgcn_cvt_pkrtz(f0, f1);
    u.p[1] = __builtin_amdgcn_cvt_pkrtz(f2, f3);
    u.p[2] = __builtin_amdgcn_cvt_pkrtz(f4, f5);
    u.p[3] = __builtin_amdgcn_cvt_pkrtz(f6, f7);
    return u.v;
}

// ---------------------------------------------------------------------------
// G = silu(X@W1^T) * (X@W3^T) -> f16 [T,F]
// NO LDS / NO BARRIERS in the K-loop: every lane loads its own MFMA fragments
// directly from global (A: f16 16B; B: 8 raw int32 = 32B, dequanted in regs).
// R5 showed the LDS-staging pipeline is latency-chain-bound (all pipes <25%);
// free-running waves overlap each other's load latency instead.
// Block = 64(m) x 128(F). 4 waves: mat = w&1 (W1/W3), nh = (w>>1)*64.
// Epilogue: one __syncthreads, W3 waves pass acc via LDS, W1 waves combine.
// Grid: flat 896 = 8 XCD x (8 m x 14 n); 8 m-siblings per XCD share weights
// through that XCD's L2 (R3: XCD swizzle cut HBM fetch 2.57 GB -> 0.41 GB).
// ---------------------------------------------------------------------------
__global__ __launch_bounds__(256, 2)
void gate_up_kernel(const _Float16* __restrict__ Xh,
                    const int* __restrict__ W1q, const float* __restrict__ sc1,
                    const float* __restrict__ zp1,
                    const int* __restrict__ W3q, const float* __restrict__ sc3,
                    const float* __restrict__ zp3,
                    _Float16* __restrict__ G)
{
    __shared__ float sEx[64 * 132];  // epilogue exchange, stride 132 (+4 banks)

    const int t = threadIdx.x, wave = t >> 6, lane = t & 63;
    const int r = lane & 15, q = lane >> 4;
    const int mat = wave & 1;           // 0 -> W1, 1 -> W3
    const int nh  = (wave >> 1) * 64;   // n-half within the 128-wide tile

    const int b = blockIdx.x;
    const int xcd = b & 7, lb = b >> 3;          // lb in [0,112)
    const int m0 = (lb & 7) * 64;                // 8 m-tiles
    const int n0 = (xcd * 14 + (lb >> 3)) * 128; // 112 n-tiles
    const int SG = H_DIM / 64;

    const int* __restrict__ Wq = mat ? W3q : W1q;
    const float* __restrict__ sc = mat ? sc3 : sc1;
    const float* __restrict__ zp = mat ? zp3 : zp1;

    f32x4 acc[4][4];
    #pragma unroll
    for (int a = 0; a < 4; ++a)
        #pragma unroll
        for (int c = 0; c < 4; ++c) acc[a][c] = (f32x4){0.f, 0.f, 0.f, 0.f};

    for (int k0 = 0; k0 < H_DIM; k0 += 64) {
        const int gidx = k0 >> 6;

        // scales for this K-group (GROUP=64 == K-tile): one per n-frag row
        float s[4], nzs[4];
        #pragma unroll
        for (int j = 0; j < 4; ++j) {
            int row = n0 + nh + j * 16 + r;
            int sidx = row * SG + gidx;
            s[j] = sc[sidx];
            nzs[j] = -zp[sidx] * s[j];
        }
        // raw B fragments: 8 ints (32 B) per (kh, j)
        int4 braw[2][4][2];
        #pragma unroll
        for (int kh = 0; kh < 2; ++kh)
            #pragma unroll
            for (int j = 0; j < 4; ++j) {
                size_t off = (size_t)(n0 + nh + j * 16 + r) * H_DIM + k0 + kh * 32 + q * 8;
                braw[kh][j][0] = *(const int4*)&Wq[off];
                braw[kh][j][1] = *(const int4*)&Wq[off + 4];
            }
        // A fragments (f16 direct)
        f16x8 av[2][4];
        #pragma unroll
        for (int kh = 0; kh < 2; ++kh)
            #pragma unroll
            for (int im = 0; im < 4; ++im)
                av[kh][im] = *(const f16x8*)&Xh[(size_t)(m0 + im * 16 + r) * H_DIM + k0 + kh * 32 + q * 8];

        #pragma unroll
        for (int kh = 0; kh < 2; ++kh)
            #pragma unroll
            for (int j = 0; j < 4; ++j) {
                f16x8 bv = dq8(braw[kh][j][0], braw[kh][j][1], s[j], nzs[j]);
                #pragma unroll
                for (int im = 0; im < 4; ++im)
                    acc[im][j] = __builtin_amdgcn_mfma_f32_16x16x32_f16(av[kh][im], bv, acc[im][j], 0, 0, 0);
            }
    }

    // ---- epilogue: W3 waves -> LDS; one barrier; W1 waves combine+store ----
    if (mat == 1) {
        #pragma unroll
        for (int im = 0; im < 4; ++im)
            #pragma unroll
            for (int j = 0; j < 4; ++j)
                #pragma unroll
                for (int reg = 0; reg < 4; ++reg)
                    sEx[(im * 16 + q * 4 + reg) * 132 + nh + j * 16 + r] = acc[im][j][reg];
    }
    __syncthreads();
    if (mat == 0) {
        #pragma unroll
        for (int im = 0; im < 4; ++im)
            #pragma unroll
            for (int j = 0; j < 4; ++j)
                #pragma unroll
                for (int reg = 0; reg < 4; ++reg) {
                    int ml = im * 16 + q * 4 + reg;
                    int nl = nh + j * 16 + r;
                    float g1 = acc[im][j][reg];
                    float g3 = sEx[ml * 132 + nl];
                    float val = g1 / (1.f + __expf(-g1)) * g3;
                    G[(size_t)(m0 + ml) * F_DIM + n0 + nl] = (_Float16)val;
                }
    }
}

// ---------------------------------------------------------------------------
// out += G @ W2^T (split-K, fp32 atomics). Same barrier-free direct-fragment
// scheme. Block = 64(m) x 128(H), 4 waves each owning a 32-wide n-strip
// (4x2 frags, 32 acc regs). Grid: flat 1024 = 8 XCD x (8 m x 4 n x 4 kseg).
// ---------------------------------------------------------------------------
__global__ __launch_bounds__(256, 2)
void down_kernel(const _Float16* __restrict__ G,
                 const int* __restrict__ W2q, const float* __restrict__ sc2,
                 const float* __restrict__ zp2,
                 float* __restrict__ Out)
{
    const int t = threadIdx.x, wave = t >> 6, lane = t & 63;
    const int r = lane & 15, q = lane >> 4;
    const int nw = wave * 32;

    const int b = blockIdx.x;
    const int xcd = b & 7, lb = b >> 3;          // lb in [0,128)
    const int m0 = (lb & 7) * 64;                // 8 m-tiles
    const int idx = lb >> 3;                     // [0,16)
    const int n0 = (xcd * 4 + (idx & 3)) * 128;  // 32 n-tiles
    const int kbeg = (idx >> 2) * (F_DIM / KSEG);
    const int kend = kbeg + (F_DIM / KSEG);
    const int SG = F_DIM / 64;

    f32x4 acc[4][2];
    #pragma unroll
    for (int a = 0; a < 4; ++a)
        #pragma unroll
        for (int c = 0; c < 2; ++c) acc[a][c] = (f32x4){0.f, 0.f, 0.f, 0.f};

    for (int k0 = kbeg; k0 < kend; k0 += 64) {
        const int gidx = k0 >> 6;

        float s[2], nzs[2];
        #pragma unroll
        for (int j = 0; j < 2; ++j) {
            int row = n0 + nw + j * 16 + r;
            int sidx = row * SG + gidx;
            s[j] = sc2[sidx];
            nzs[j] = -zp2[sidx] * s[j];
        }
        int4 braw[2][2][2];
        #pragma unroll
        for (int kh = 0; kh < 2; ++kh)
            #pragma unroll
            for (int j = 0; j < 2; ++j) {
                size_t off = (size_t)(n0 + nw + j * 16 + r) * F_DIM + k0 + kh * 32 + q * 8;
                braw[kh][j][0] = *(const int4*)&W2q[off];
                braw[kh][j][1] = *(const int4*)&W2q[off + 4];
            }
        f16x8 av[2][4];
        #pragma unroll
        for (int kh = 0; kh < 2; ++kh)
            #pragma unroll
            for (int im = 0; im < 4; ++im)
                av[kh][im] = *(const f16x8*)&G[(size_t)(m0 + im * 16 + r) * F_DIM + k0 + kh * 32 + q * 8];

        #pragma unroll
        for (int kh = 0; kh < 2; ++kh)
            #pragma unroll
            for (int j = 0; j < 2; ++j) {
                f16x8 bv = dq8(braw[kh][j][0], braw[kh][j][1], s[j], nzs[j]);
                #pragma unroll
                for (int im = 0; im < 4; ++im)
                    acc[im][j] = __builtin_amdgcn_mfma_f32_16x16x32_f16(av[kh][im], bv, acc[im][j], 0, 0, 0);
            }
    }

    #pragma unroll
    for (int im = 0; im < 4; ++im)
        #pragma unroll
        for (int j = 0; j < 2; ++j)
            #pragma unroll
            for (int reg = 0; reg < 4; ++reg) {
                int m = m0 + im * 16 + q * 4 + reg;
                int h = n0 + nw + j * 16 + r;
                atomicAdd(&Out[(size_t)m * H_DIM + h], acc[im][j][reg]);
            }
}

extern "C" void kernel_launch(void* const* d_in, const int* in_sizes, int n_in,
                              void* d_out, int out_size, void* d_ws, size_t ws_size,
                              hipStream_t stream) {
    const float* X   = (const float*)d_in[0];
    const int*   W1q = (const int*)d_in[1];
    const float* s1  = (const float*)d_in[2];
    const float* z1  = (const float*)d_in[3];
    const int*   W3q = (const int*)d_in[4];
    const float* s3  = (const float*)d_in[5];
    const float* z3  = (const float*)d_in[6];
    const int*   W2q = (const int*)d_in[7];
    const float* s2  = (const float*)d_in[8];
    const float* z2  = (const float*)d_in[9];
    float* Out = (float*)d_out;

    _Float16* Xh = (_Float16*)d_ws;                          // 4 MB
    _Float16* G  = (_Float16*)((char*)d_ws + (4 << 20));     // 14.7 MB

    zero_out<<<2048, 256, 0, stream>>>((float4*)Out);
    cvt_x<<<2048, 256, 0, stream>>>(X, Xh);
    gate_up_kernel<<<896, 256, 0, stream>>>(Xh, W1q, s1, z1, W3q, s3, z3, G);
    down_kernel<<<1024, 256, 0, stream>>>(G, W2q, s2, z2, Out);
}

// Round 8
// 1196.715 us; speedup vs baseline: 1.9569x; 1.9569x over previous
//
#include <hip/hip_runtime.h>
#include <hip/hip_bf16.h>

#define T_DIM 512
#define H_DIM 4096
#define F_DIM 14336
#define KSEG  4   // split-K segments for down GEMM (14336/4 = 3584 = 56 x 64)

typedef __fp16 f16x8 __attribute__((ext_vector_type(8)));
typedef __fp16 f16x2 __attribute__((ext_vector_type(2)));
typedef float f32x4 __attribute__((ext_vector_type(4)));

// Barrier waiting only on LDS ops (lgkmcnt(0), vmcnt(63)): global register
// prefetch stays in flight across it. Proven correct in R5. imm 0xC07F.
__device__ __forceinline__ void barrier_lgkm() {
    __asm__ __volatile__("" ::: "memory");
    __builtin_amdgcn_s_waitcnt(0xC07F);
    __builtin_amdgcn_s_barrier();
    __asm__ __volatile__("" ::: "memory");
}

// Zero d_out (harness poisons with 0xAA; down_kernel accumulates via atomics).
__global__ __launch_bounds__(256) void zero_out(float4* __restrict__ out) {
    out[blockIdx.x * 256 + threadIdx.x] = make_float4(0.f, 0.f, 0.f, 0.f);
}

// X fp32 -> f16 once.
__global__ __launch_bounds__(256) void cvt_x(const float* __restrict__ X,
                                             _Float16* __restrict__ Xh) {
    int i = (blockIdx.x * 256 + threadIdx.x) * 4;
    float4 v = *(const float4*)&X[i];
    union { struct { f16x2 a, b; } p; uint2 u; } u;
    u.p.a = __builtin_amdgcn_cvt_pkrtz(v.x, v.y);
    u.p.b = __builtin_amdgcn_cvt_pkrtz(v.z, v.w);
    *(uint2*)&Xh[i] = u.u;
}

// Dequant 4 int32 HQQ values -> 4 f16 (packed RTZ converts, cheap).
__device__ __forceinline__ ushort4 dq4(int4 qv, float s, float nzs) {
    union { struct { f16x2 lo, hi; } h; ushort4 u; } u;
    u.h.lo = __builtin_amdgcn_cvt_pkrtz(fmaf((float)qv.x, s, nzs),
                                        fmaf((float)qv.y, s, nzs));
    u.h.hi = __builtin_amdgcn_cvt_pkrtz(fmaf((float)qv.z, s, nzs),
                                        fmaf((float)qv.w, s, nzs));
    return u.u;
}

// ---------------------------------------------------------------------------
// G = silu(X@W1^T) * (X@W3^T) -> f16 [T,F]
// R4 structure + DOUBLE-BUFFERED LDS, one lgkm-barrier per iter:
//   iter i: MFMA on buf[p] (tile i)  ||  dequant regs(tile i+1)->buf[p^1]
//           ||  issue global loads tile i+2 -> regs
// Tile M128 x N64 x K64(=GROUP). 4 waves: wave&1 = m-half, wave>>1 = matrix.
// Grid: flat 896, XCD-swizzled (4 m-siblings per XCD share the weight stream).
// LDS 2 x 36864 = 73728 B -> 2 blocks/CU.
// ---------------------------------------------------------------------------
__global__ __launch_bounds__(256, 2)
void gate_up_kernel(const _Float16* __restrict__ Xh,
                    const int* __restrict__ W1q, const float* __restrict__ sc1,
                    const float* __restrict__ zp1,
                    const int* __restrict__ W3q, const float* __restrict__ sc3,
                    const float* __restrict__ zp3,
                    _Float16* __restrict__ G)
{
    constexpr int LK = 72;  // f16 elems/row: 144 B stride, 16B-aligned
    // per buf: rows 0..127 = X, 128..191 = W1, 192..255 = W3
    __shared__ __align__(16) unsigned short smem[2][256 * LK];

    const int t = threadIdx.x, wave = t >> 6, lane = t & 63;
    const int r = lane & 15, q = lane >> 4;
    const int mh = (wave & 1) * 64, mat = wave >> 1;

    const int b = blockIdx.x;
    const int xcd = b & 7, lb = b >> 3;         // lb in [0,112)
    const int m0 = (lb & 3) * 128;
    const int n0 = (xcd * 28 + (lb >> 2)) * 64; // n-tile in [0,224)
    const int SG = H_DIM / 64;

    const int xrow = t >> 3, xch = (t & 7) * 8;   // X: rows xrow+32i, 16B chunk
    const int wrow = t >> 4, wc = (t & 15) * 4;   // W: rows wrow+16i, 4 int32

    int4 rX[4], rW1[4], rW3[4];

    auto load_tile = [&](int k0) {
        #pragma unroll
        for (int i = 0; i < 4; ++i)
            rX[i] = *(const int4*)&Xh[(size_t)(m0 + xrow + 32 * i) * H_DIM + k0 + xch];
        #pragma unroll
        for (int i = 0; i < 4; ++i) {
            size_t off = (size_t)(n0 + wrow + 16 * i) * H_DIM + k0 + wc;
            rW1[i] = *(const int4*)&W1q[off];
            rW3[i] = *(const int4*)&W3q[off];
        }
    };
    auto stage = [&](unsigned short* buf, int gidx) {
        unsigned short* sX  = buf;
        unsigned short* sW1 = buf + 128 * LK;
        unsigned short* sW3 = buf + 192 * LK;
        #pragma unroll
        for (int i = 0; i < 4; ++i)
            *(int4*)&sX[(xrow + 32 * i) * LK + xch] = rX[i];
        #pragma unroll
        for (int i = 0; i < 4; ++i) {
            int row = wrow + 16 * i;
            int sidx = (n0 + row) * SG + gidx;
            float s = sc1[sidx], nzs = -zp1[sidx] * s;
            *(ushort4*)&sW1[row * LK + wc] = dq4(rW1[i], s, nzs);
            s = sc3[sidx]; nzs = -zp3[sidx] * s;
            *(ushort4*)&sW3[row * LK + wc] = dq4(rW3[i], s, nzs);
        }
    };

    f32x4 acc[4][4];
    #pragma unroll
    for (int a = 0; a < 4; ++a)
        #pragma unroll
        for (int c = 0; c < 4; ++c) acc[a][c] = (f32x4){0.f, 0.f, 0.f, 0.f};

    // prologue: tile0 -> buf0; tile1 -> regs
    load_tile(0);
    stage(smem[0], 0);
    load_tile(64);
    barrier_lgkm();

    int p = 0;
    for (int k0 = 0; k0 < H_DIM; k0 += 64) {
        // MFMA on buf[p] (tile k0)
        const unsigned short* sX = smem[p];
        const unsigned short* sB = smem[p] + (mat ? 192 * LK : 128 * LK);
        #pragma unroll
        for (int kh = 0; kh < 2; ++kh) {
            const int kb = kh * 32 + q * 8;
            f16x8 av[4], bv[4];
            #pragma unroll
            for (int im = 0; im < 4; ++im)
                av[im] = *(const f16x8*)&sX[(mh + im * 16 + r) * LK + kb];
            #pragma unroll
            for (int j = 0; j < 4; ++j)
                bv[j] = *(const f16x8*)&sB[(j * 16 + r) * LK + kb];
            #pragma unroll
            for (int im = 0; im < 4; ++im)
                #pragma unroll
                for (int j = 0; j < 4; ++j)
                    acc[im][j] = __builtin_amdgcn_mfma_f32_16x16x32_f16(av[im], bv[j], acc[im][j], 0, 0, 0);
        }
        // stage tile k0+64 from regs; issue loads for tile k0+128
        int k1 = k0 + 64;
        if (k1 < H_DIM) {
            stage(smem[p ^ 1], k1 >> 6);
            if (k1 + 64 < H_DIM) load_tile(k1 + 64);
            barrier_lgkm();
        }
        p ^= 1;
    }

    // ---- epilogue: W3 waves -> LDS (smem[0], untouched by last MFMA which
    // reads smem[1]); one barrier; W1 waves combine+store ----
    float* sEx = (float*)&smem[0][0];  // 128 x 65 floats = 33280 B
    if (mat == 1) {
        #pragma unroll
        for (int im = 0; im < 4; ++im)
            #pragma unroll
            for (int j = 0; j < 4; ++j)
                #pragma unroll
                for (int reg = 0; reg < 4; ++reg)
                    sEx[(mh + im * 16 + q * 4 + reg) * 65 + j * 16 + r] = acc[im][j][reg];
    }
    __syncthreads();
    if (mat == 0) {
        #pragma unroll
        for (int im = 0; im < 4; ++im)
            #pragma unroll
            for (int j = 0; j < 4; ++j)
                #pragma unroll
                for (int reg = 0; reg < 4; ++reg) {
                    int ml = mh + im * 16 + q * 4 + reg;
                    int nl = j * 16 + r;
                    float g1 = acc[im][j][reg];
                    float g3 = sEx[ml * 65 + nl];
                    float val = g1 / (1.f + __expf(-g1)) * g3;
                    G[(size_t)(m0 + ml) * F_DIM + n0 + nl] = (_Float16)val;
                }
    }
}

// ---------------------------------------------------------------------------
// out += G @ W2^T (split-K, fp32 atomics). Same double-buffered pipeline.
// Tile M128 x N128 x K64, 4 waves x 64x64. Grid: flat 512 = 8 XCD x
// (4 m x 4 n x 4 kseg) -> exactly 2 blocks/CU. LDS 73728 B.
// ---------------------------------------------------------------------------
__global__ __launch_bounds__(256, 2)
void down_kernel(const _Float16* __restrict__ G,
                 const int* __restrict__ W2q, const float* __restrict__ sc2,
                 const float* __restrict__ zp2,
                 float* __restrict__ Out)
{
    constexpr int LK = 72;
    // per buf: rows 0..127 = A (G), 128..255 = W2
    __shared__ __align__(16) unsigned short smem[2][256 * LK];

    const int t = threadIdx.x, wave = t >> 6, lane = t & 63;
    const int r = lane & 15, q = lane >> 4;
    const int wm = (wave & 1) * 64, wn = (wave >> 1) * 64;

    const int b = blockIdx.x;
    const int xcd = b & 7, lb = b >> 3;          // lb in [0,64)
    const int m0 = (lb & 3) * 128;
    const int rest = lb >> 2;                    // [0,16)
    const int n0 = (xcd * 4 + (rest & 3)) * 128; // 32 n-tiles
    const int kbeg = (rest >> 2) * (F_DIM / KSEG);
    const int kend = kbeg + (F_DIM / KSEG);
    const int SG = F_DIM / 64;

    const int arow = t >> 3, ach = (t & 7) * 8;
    const int wrow = t >> 4, wc = (t & 15) * 4;

    int4 rA[4], rW[8];

    auto load_tile = [&](int k0) {
        #pragma unroll
        for (int i = 0; i < 4; ++i)
            rA[i] = *(const int4*)&G[(size_t)(m0 + arow + 32 * i) * F_DIM + k0 + ach];
        #pragma unroll
        for (int i = 0; i < 8; ++i)
            rW[i] = *(const int4*)&W2q[(size_t)(n0 + wrow + 16 * i) * F_DIM + k0 + wc];
    };
    auto stage = [&](unsigned short* buf, int gidx) {
        unsigned short* sA = buf;
        unsigned short* sW = buf + 128 * LK;
        #pragma unroll
        for (int i = 0; i < 4; ++i)
            *(int4*)&sA[(arow + 32 * i) * LK + ach] = rA[i];
        #pragma unroll
        for (int i = 0; i < 8; ++i) {
            int row = wrow + 16 * i;
            int sidx = (n0 + row) * SG + gidx;
            float s = sc2[sidx], nzs = -zp2[sidx] * s;
            *(ushort4*)&sW[row * LK + wc] = dq4(rW[i], s, nzs);
        }
    };

    f32x4 acc[4][4];
    #pragma unroll
    for (int a = 0; a < 4; ++a)
        #pragma unroll
        for (int c = 0; c < 4; ++c) acc[a][c] = (f32x4){0.f, 0.f, 0.f, 0.f};

    load_tile(kbeg);
    stage(smem[0], kbeg >> 6);
    load_tile(kbeg + 64);
    barrier_lgkm();

    int p = 0;
    for (int k0 = kbeg; k0 < kend; k0 += 64) {
        const unsigned short* sA = smem[p];
        const unsigned short* sW = smem[p] + 128 * LK;
        #pragma unroll
        for (int kh = 0; kh < 2; ++kh) {
            const int kb = kh * 32 + q * 8;
            f16x8 av[4], bv[4];
            #pragma unroll
            for (int im = 0; im < 4; ++im)
                av[im] = *(const f16x8*)&sA[(wm + im * 16 + r) * LK + kb];
            #pragma unroll
            for (int j = 0; j < 4; ++j)
                bv[j] = *(const f16x8*)&sW[(wn + j * 16 + r) * LK + kb];
            #pragma unroll
            for (int im = 0; im < 4; ++im)
                #pragma unroll
                for (int j = 0; j < 4; ++j)
                    acc[im][j] = __builtin_amdgcn_mfma_f32_16x16x32_f16(av[im], bv[j], acc[im][j], 0, 0, 0);
        }
        int k1 = k0 + 64;
        if (k1 < kend) {
            stage(smem[p ^ 1], k1 >> 6);
            if (k1 + 64 < kend) load_tile(k1 + 64);
            barrier_lgkm();
        }
        p ^= 1;
    }

    #pragma unroll
    for (int im = 0; im < 4; ++im)
        #pragma unroll
        for (int j = 0; j < 4; ++j)
            #pragma unroll
            for (int reg = 0; reg < 4; ++reg) {
                int m = m0 + wm + im * 16 + q * 4 + reg;
                int h = n0 + wn + j * 16 + r;
                atomicAdd(&Out[(size_t)m * H_DIM + h], acc[im][j][reg]);
            }
}

extern "C" void kernel_launch(void* const* d_in, const int* in_sizes, int n_in,
                              void* d_out, int out_size, void* d_ws, size_t ws_size,
                              hipStream_t stream) {
    const float* X   = (const float*)d_in[0];
    const int*   W1q = (const int*)d_in[1];
    const float* s1  = (const float*)d_in[2];
    const float* z1  = (const float*)d_in[3];
    const int*   W3q = (const int*)d_in[4];
    const float* s3  = (const float*)d_in[5];
    const float* z3  = (const float*)d_in[6];
    const int*   W2q = (const int*)d_in[7];
    const float* s2  = (const float*)d_in[8];
    const float* z2  = (const float*)d_in[9];
    float* Out = (float*)d_out;

    _Float16* Xh = (_Float16*)d_ws;                       // 4 MB
    _Float16* G  = (_Float16*)((char*)d_ws + (4 << 20));  // 14.7 MB

    zero_out<<<2048, 256, 0, stream>>>((float4*)Out);
    cvt_x<<<2048, 256, 0, stream>>>(X, Xh);
    gate_up_kernel<<<896, 256, 0, stream>>>(Xh, W1q, s1, z1, W3q, s3, z3, G);
    down_kernel<<<512, 256, 0, stream>>>(G, W2q, s2, z2, Out);
}